// Round 1
// baseline (2996.362 us; speedup 1.0000x reference)
//
#include <hip/hip_runtime.h>

#define Bc 256
#define Tc 325
#define NSc 39
#define COc 64
#define NCc 20
#define ESc 117
#define ETc 648

// workspace layout in 4-byte units
#define WS_ROFF_S   0          // 40 ints
#define WS_SRC_S    64         // 117 ints
#define WS_NRM_S    192        // 117 f
#define WS_DINV_S   320        // 39 f
#define WS_ROFF_T   384        // 326 ints
#define WS_SRC_T    768        // 648 ints
#define WS_NRM_T    1472       // 648 f
#define WS_DINV_T   2176       // 325 f
#define WS_WT       2560       // 416000 f  (tfc1_w transposed [20][20800])
#define WS_OUTS     418560     // 5120 f
#define WS_OUTT     423680     // 5120 f

// ---------------- prep: CSR (by dst) + symmetric norm for both graphs ----------------
__global__ void prep_graph(const int* __restrict__ eiS, const int* __restrict__ eiT,
                           int* __restrict__ wsI, float* __restrict__ wsF) {
  const int which = blockIdx.x;
  const int* ei = which ? eiT : eiS;
  const int nE = which ? ETc : ESc;
  const int nN = which ? Tc : NSc;
  int* roff = wsI + (which ? WS_ROFF_T : WS_ROFF_S);
  int* srcO = wsI + (which ? WS_SRC_T : WS_SRC_S);
  float* nrmO = wsF + (which ? WS_NRM_T : WS_NRM_S);
  float* dinv = wsF + (which ? WS_DINV_T : WS_DINV_S);
  const int* src = ei;
  const int* dst = ei + nE;
  for (int n = threadIdx.x; n < nN; n += blockDim.x) {
    int deg = 0, before = 0;
    for (int e = 0; e < nE; ++e) { deg += (dst[e] == n); before += (dst[e] < n); }
    roff[n] = before;
    if (n == nN - 1) roff[nN] = before + deg;
    dinv[n] = (deg > 0) ? (1.0f / sqrtf((float)deg)) : 0.0f;
  }
  __syncthreads();
  for (int n = threadIdx.x; n < nN; n += blockDim.x) {
    int cur = roff[n];
    float dn = dinv[n];
    for (int e = 0; e < nE; ++e) {
      if (dst[e] == n) { srcO[cur] = src[e]; nrmO[cur] = dinv[src[e]] * dn; ++cur; }
    }
  }
}

// ---------------- prep: transpose tfc1_w [20800][20] -> [20][20800] ----------------
__global__ void prep_wt(const float* __restrict__ w, float* __restrict__ wT) {
  int i = blockIdx.x * 256 + threadIdx.x;
  if (i < NCc * Tc * COc) {
    int j = i / (Tc * COc);
    int p = i - j * (Tc * COc);
    wT[i] = w[p * NCc + j];
  }
}

// ---------------- spatial path: 1 batch per WG, fc1_w register-resident ----------------
__global__ __launch_bounds__(256, 1)
void spatial_kernel(const float* __restrict__ data,
                    const int* __restrict__ roff, const int* __restrict__ srcC,
                    const float* __restrict__ nrmC,
                    const float* __restrict__ convW, const float* __restrict__ convB,
                    const float* __restrict__ fcW, const float* __restrict__ fcB,
                    float* __restrict__ outS)
{
  __shared__ __align__(16) float feats[NSc][16];
  __shared__ unsigned long long spkw[NSc];
  __shared__ int lroff[NSc + 1];
  __shared__ int lsrc[ESc];
  __shared__ float lnrm[ESc];

  const int tid = threadIdx.x;
  const int lane = tid & 63;
  const int wv = tid >> 6;
  const int b = blockIdx.x;

  if (tid < NSc + 1) lroff[tid] = roff[tid];
  if (tid < ESc) { lsrc[tid] = srcC[tid]; lnrm[tid] = nrmC[tid]; }

  float wc[16];
#pragma unroll
  for (int r = 0; r < 16; ++r) wc[r] = convW[r * COc + lane];
  const float bcv = convB[lane];

  // lane = channel; wave owns outputs j = wv*5..wv*5+4; flat pos = node*64 + lane
  float wfc[NSc * 5];
#pragma unroll
  for (int i = 0; i < NSc; ++i)
#pragma unroll
    for (int jj = 0; jj < 5; ++jj)
      wfc[i * 5 + jj] = fcW[(i * COc + lane) * NCc + wv * 5 + jj];

  float bj[5];
#pragma unroll
  for (int jj = 0; jj < 5; ++jj) bj[jj] = fcB[wv * 5 + jj];

  float cm[10];
#pragma unroll
  for (int q = 0; q < 10; ++q) cm[q] = 0.0f;
  float hm[5] = {0,0,0,0,0}, hsum[5] = {0,0,0,0,0};
  const int nq = (wv < 3) ? 10 : 9;

  const float* dbase = data + (size_t)b * (2 * NSc * 2 * Tc);
  __syncthreads();

  for (int t = 0; t < Tc; ++t) {
    // stage x_t (h0) into feats cols 0..3
    if (tid < NSc * 4) {
      int n = tid >> 2, c = tid & 3;
      int nn = n + ((c & 2) ? NSc : 0);
      feats[n][c] = dbase[(nn * 2 + (c & 1)) * Tc + t];
    }
    __syncthreads();
    // hops: cols 4k+c from cols 4(k-1)+c
#pragma unroll
    for (int k = 1; k <= 3; ++k) {
      if (tid < NSc * 4) {
        int n = tid >> 2, c = tid & 3;
        float v = 0.0f;
        for (int e = lroff[n]; e < lroff[n + 1]; ++e)
          v += lnrm[e] * feats[lsrc[e]][(k - 1) * 4 + c];
        feats[n][k * 4 + c] = v;
      }
      __syncthreads();
    }
    // conv + LIF on c_mem; spike word per node via ballot (bit = channel = lane)
#pragma unroll
    for (int q = 0; q < 10; ++q) {
      if (q < nq) {
        int i = wv + 4 * q;
        const float4* f4 = (const float4*)feats[i];
        float fv[16];
        *(float4*)&fv[0]  = f4[0];
        *(float4*)&fv[4]  = f4[1];
        *(float4*)&fv[8]  = f4[2];
        *(float4*)&fv[12] = f4[3];
        float acc = bcv;
#pragma unroll
        for (int r = 0; r < 16; ++r) acc = fmaf(fv[r], wc[r], acc);
        float old = cm[q];
        float m = (old * 0.2f) * ((old > 0.5f) ? 0.0f : 1.0f) + acc;
        cm[q] = m;
        unsigned long long wd = __ballot(m > 0.5f);
        if (lane == 0) spkw[i] = wd;
      }
    }
    __syncthreads();
    // fc: binary-gated accumulation with register weights
    float acc5[5] = {0,0,0,0,0};
#pragma unroll
    for (int i = 0; i < NSc; ++i) {
      unsigned long long wd = spkw[i];
      float g = (float)((wd >> lane) & 1ull);
#pragma unroll
      for (int jj = 0; jj < 5; ++jj)
        acc5[jj] = fmaf(g, wfc[i * 5 + jj], acc5[jj]);
    }
#pragma unroll
    for (int off = 32; off >= 1; off >>= 1)
#pragma unroll
      for (int jj = 0; jj < 5; ++jj)
        acc5[jj] += __shfl_xor(acc5[jj], off, 64);
#pragma unroll
    for (int jj = 0; jj < 5; ++jj) {
      float m = hm[jj];
      m = (m * 0.2f) * ((m > 0.5f) ? 0.0f : 1.0f) + acc5[jj] + bj[jj];
      hm[jj] = m;
      hsum[jj] += (m > 0.5f) ? 1.0f : 0.0f;
    }
  }
  if (lane == 0) {
#pragma unroll
    for (int jj = 0; jj < 5; ++jj)
      outS[b * NCc + wv * 5 + jj] = hsum[jj] / (float)Tc;
  }
}

// ---------------- temporal path: 1 batch per WG, t_mem in VGPRs, tfc1_w streamed ----------------
__global__ __launch_bounds__(256, 1)
void temporal_kernel(const float* __restrict__ data,
                     const int* __restrict__ roff, const int* __restrict__ srcC,
                     const float* __restrict__ nrmC,
                     const float* __restrict__ convW, const float* __restrict__ convB,
                     const float* __restrict__ wT, const float* __restrict__ fcB,
                     float* __restrict__ outT)
{
  __shared__ __align__(16) float feats[Tc][16];       // 20.8 KB
  __shared__ unsigned long long spkw[Tc];             // 2.6 KB
  __shared__ int lroff[Tc + 1];
  __shared__ int lsrc[ETc];
  __shared__ float lnrm[ETc];

  const int tid = threadIdx.x;
  const int lane = tid & 63;
  const int wv = tid >> 6;
  const int b = blockIdx.x;

  for (int n = tid; n < Tc + 1; n += 256) lroff[n] = roff[n];
  for (int e = tid; e < ETc; e += 256) { lsrc[e] = srcC[e]; lnrm[e] = nrmC[e]; }

  float wc[16];
#pragma unroll
  for (int r = 0; r < 16; ++r) wc[r] = convW[r * COc + lane];
  const float bcv = convB[lane];
  float bj[5];
#pragma unroll
  for (int jj = 0; jj < 5; ++jj) bj[jj] = fcB[wv * 5 + jj];

  float tm[82];
#pragma unroll
  for (int q = 0; q < 82; ++q) tm[q] = 0.0f;
  float hm[5] = {0,0,0,0,0}, hsum[5] = {0,0,0,0,0};

  const float* dbase = data + (size_t)b * (2 * NSc * 2 * Tc);
  const float* wbase = wT + (size_t)(wv * 5) * (Tc * COc) + lane;

  __syncthreads();

  for (int s = 0; s < NSc; ++s) {
    // stage x_s: [325][4], coalesced in t
#pragma unroll
    for (int k2 = 0; k2 < 6; ++k2) {
      int idx = tid + 256 * k2;
      if (idx < Tc * 4) {
        int c = idx / Tc, t = idx - c * Tc;
        int nn = (c & 2) ? (NSc + s) : s;
        feats[t][c] = dbase[(nn * 2 + (c & 1)) * Tc + t];
      }
    }
    __syncthreads();
#pragma unroll
    for (int k = 1; k <= 3; ++k) {
      for (int k2 = 0; k2 < 6; ++k2) {
        int idx = tid + 256 * k2;
        if (idx < Tc * 4) {
          int t = idx >> 2, c = idx & 3;
          float v = 0.0f;
          for (int e = lroff[t]; e < lroff[t + 1]; ++e)
            v += lnrm[e] * feats[lsrc[e]][(k - 1) * 4 + c];
          feats[t][k * 4 + c] = v;
        }
      }
      __syncthreads();
    }
    // conv + LIF (t_mem in registers, static unroll)
#pragma unroll
    for (int q = 0; q < 82; ++q) {
      int i = wv + 4 * q;
      if (i < Tc) {
        const float4* f4 = (const float4*)feats[i];
        float fv[16];
        *(float4*)&fv[0]  = f4[0];
        *(float4*)&fv[4]  = f4[1];
        *(float4*)&fv[8]  = f4[2];
        *(float4*)&fv[12] = f4[3];
        float acc = bcv;
#pragma unroll
        for (int r = 0; r < 16; ++r) acc = fmaf(fv[r], wc[r], acc);
        float old = tm[q];
        float m = (old * 0.2f) * ((old > 0.5f) ? 0.0f : 1.0f) + acc;
        tm[q] = m;
        unsigned long long wd = __ballot(m > 0.5f);
        if (lane == 0) spkw[i] = wd;
      }
    }
    __syncthreads();
    // fc: stream transposed weights from L2, coalesced per wave
    float acc5[5] = {0,0,0,0,0};
#pragma unroll 5
    for (int i = 0; i < Tc; ++i) {
      unsigned long long wd = spkw[i];
      float g = (float)((wd >> lane) & 1ull);
#pragma unroll
      for (int jj = 0; jj < 5; ++jj)
        acc5[jj] = fmaf(g, wbase[(size_t)jj * (Tc * COc) + i * COc], acc5[jj]);
    }
#pragma unroll
    for (int off = 32; off >= 1; off >>= 1)
#pragma unroll
      for (int jj = 0; jj < 5; ++jj)
        acc5[jj] += __shfl_xor(acc5[jj], off, 64);
#pragma unroll
    for (int jj = 0; jj < 5; ++jj) {
      float m = hm[jj];
      m = (m * 0.2f) * ((m > 0.5f) ? 0.0f : 1.0f) + acc5[jj] + bj[jj];
      hm[jj] = m;
      hsum[jj] += (m > 0.5f) ? 1.0f : 0.0f;
    }
  }
  if (lane == 0) {
#pragma unroll
    for (int jj = 0; jj < 5; ++jj)
      outT[b * NCc + wv * 5 + jj] = hsum[jj] / (float)NSc;
  }
}

__global__ void combine_kernel(const float* __restrict__ a, const float* __restrict__ c,
                               float* __restrict__ o) {
  int i = blockIdx.x * 256 + threadIdx.x;
  if (i < Bc * NCc) o[i] = (a[i] + c[i]) * 0.5f;
}

extern "C" void kernel_launch(void* const* d_in, const int* in_sizes, int n_in,
                              void* d_out, int out_size, void* d_ws, size_t ws_size,
                              hipStream_t stream) {
  const float* data = (const float*)d_in[0];
  const int*   eiS  = (const int*)d_in[1];
  const int*   eiT  = (const int*)d_in[2];
  const float* c1w  = (const float*)d_in[3];
  const float* c1b  = (const float*)d_in[4];
  const float* c2w  = (const float*)d_in[5];
  const float* c2b  = (const float*)d_in[6];
  const float* f1w  = (const float*)d_in[7];
  const float* f1b  = (const float*)d_in[8];
  const float* tf1w = (const float*)d_in[9];
  const float* tf1b = (const float*)d_in[10];
  float* out = (float*)d_out;
  int* wsI = (int*)d_ws;
  float* wsF = (float*)d_ws;

  prep_graph<<<2, 256, 0, stream>>>(eiS, eiT, wsI, wsF);
  prep_wt<<<(NCc * Tc * COc + 255) / 256, 256, 0, stream>>>(tf1w, wsF + WS_WT);
  spatial_kernel<<<Bc, 256, 0, stream>>>(data, wsI + WS_ROFF_S, wsI + WS_SRC_S,
                                         wsF + WS_NRM_S, c1w, c1b, f1w, f1b,
                                         wsF + WS_OUTS);
  temporal_kernel<<<Bc, 256, 0, stream>>>(data, wsI + WS_ROFF_T, wsI + WS_SRC_T,
                                          wsF + WS_NRM_T, c2w, c2b, wsF + WS_WT,
                                          tf1b, wsF + WS_OUTT);
  combine_kernel<<<(Bc * NCc + 255) / 256, 256, 0, stream>>>(wsF + WS_OUTS,
                                                             wsF + WS_OUTT, out);
}

// Round 2
// 2011.394 us; speedup vs baseline: 1.4897x; 1.4897x over previous
//
#include <hip/hip_runtime.h>

#define Bc 256
#define Tc 325
#define NSc 39
#define COc 64
#define NCc 20
#define ESc 117
#define ETc 648
#define MAXDEG 16

// workspace layout in 4-byte units
#define WS_ROFF_T 0        // 326 ints
#define WS_SRC_T  384      // 648 ints
#define WS_NRM_T  1088     // 648 f
#define WS_DINV_T 1792     // 325 f
#define WS_DINV_S 2176     // 39 f
#define WS_SRCP   2240     // 39*16 ints (padded spatial CSR src)
#define WS_NRMP   2880     // 39*16 f    (padded spatial CSR norm)
#define WS_WT     3584     // 416000 f   (tfc1_w transposed [20][20800])
#define WS_OUTS   419584   // 5120 f
#define WS_OUTT   424704   // 5120 f

// ---------------- prep: graphs ----------------
__global__ void prep_graph(const int* __restrict__ eiS, const int* __restrict__ eiT,
                           int* __restrict__ wsI, float* __restrict__ wsF) {
  if (blockIdx.x == 0) {
    // spatial: degree-padded CSR (MAXDEG) + symmetric norm
    const int* src = eiS;
    const int* dst = eiS + ESc;
    float* dinv = wsF + WS_DINV_S;
    int* srcP = wsI + WS_SRCP;
    float* nrmP = wsF + WS_NRMP;
    for (int n = threadIdx.x; n < NSc; n += blockDim.x) {
      int deg = 0;
      for (int e = 0; e < ESc; ++e) deg += (dst[e] == n);
      dinv[n] = (deg > 0) ? (1.0f / sqrtf((float)deg)) : 0.0f;
    }
    __syncthreads();
    for (int n = threadIdx.x; n < NSc; n += blockDim.x) {
      float dn = dinv[n];
      int cur = 0;
      for (int e = 0; e < ESc; ++e) {
        if (dst[e] == n && cur < MAXDEG) {
          srcP[n * MAXDEG + cur] = src[e];
          nrmP[n * MAXDEG + cur] = dinv[src[e]] * dn;
          ++cur;
        }
      }
      for (; cur < MAXDEG; ++cur) {
        srcP[n * MAXDEG + cur] = 0;
        nrmP[n * MAXDEG + cur] = 0.0f;
      }
    }
  } else {
    // temporal: CSR by dst + symmetric norm
    const int* src = eiT;
    const int* dst = eiT + ETc;
    int* roff = wsI + WS_ROFF_T;
    int* srcO = wsI + WS_SRC_T;
    float* nrmO = wsF + WS_NRM_T;
    float* dinv = wsF + WS_DINV_T;
    for (int n = threadIdx.x; n < Tc; n += blockDim.x) {
      int deg = 0, before = 0;
      for (int e = 0; e < ETc; ++e) { deg += (dst[e] == n); before += (dst[e] < n); }
      roff[n] = before;
      if (n == Tc - 1) roff[Tc] = before + deg;
      dinv[n] = (deg > 0) ? (1.0f / sqrtf((float)deg)) : 0.0f;
    }
    __syncthreads();
    for (int n = threadIdx.x; n < Tc; n += blockDim.x) {
      int cur = roff[n];
      float dn = dinv[n];
      for (int e = 0; e < ETc; ++e) {
        if (dst[e] == n) { srcO[cur] = src[e]; nrmO[cur] = dinv[src[e]] * dn; ++cur; }
      }
    }
  }
}

// ---------------- prep: transpose tfc1_w [20800][20] -> [20][20800] ----------------
__global__ void prep_wt(const float* __restrict__ w, float* __restrict__ wT) {
  int i = blockIdx.x * 256 + threadIdx.x;
  if (i < NCc * Tc * COc) {
    int j = i / (Tc * COc);
    int p = i - j * (Tc * COc);
    wT[i] = w[p * NCc + j];
  }
}

// ---------------- fused LIF kernel: path = bid&1, batch = bid>>1 ----------------
__global__ __launch_bounds__(512, 2)
void lif_kernel(const float* __restrict__ data,
                const int* __restrict__ roffT, const int* __restrict__ srcT,
                const float* __restrict__ nrmT,
                const int* __restrict__ srcP, const float* __restrict__ nrmP,
                const float* __restrict__ c1w, const float* __restrict__ c1b,
                const float* __restrict__ c2w, const float* __restrict__ c2b,
                const float* __restrict__ f1w, const float* __restrict__ f1b,
                const float* __restrict__ wT, const float* __restrict__ tf1b,
                float* __restrict__ outS, float* __restrict__ outT)
{
  __shared__ float featsS[16][40];
  __shared__ unsigned long long spkwS[NSc];
  __shared__ float featsT[Tc][20];
  __shared__ unsigned long long spkwT[Tc];
  __shared__ int lroff[Tc + 1];
  __shared__ int lsrc[ETc];
  __shared__ float lnrm[ETc];

  const int tid = threadIdx.x;
  const int lane = tid & 63;
  const int w = tid >> 6;
  const int path = blockIdx.x & 1;
  const int b = blockIdx.x >> 1;

  // per-wave output assignment: waves 0-3 -> 3 outputs, waves 4-7 -> 2 outputs (=20)
  const int j0 = (w < 4) ? w * 3 : 12 + (w - 4) * 2;
  const int jn = (w < 4) ? 3 : 2;

  const float* dbase = data + (size_t)b * (2 * NSc * 2 * Tc);

  if (path == 0) {
    // ================= SPATIAL =================
    float wc[16];
#pragma unroll
    for (int r = 0; r < 16; ++r) wc[r] = c1w[r * COc + lane];
    const float bcv = c1b[lane];

    // fc weights register-resident: 39 nodes x up to 3 outputs (zero-pad)
    float wfcr[NSc * 3];
#pragma unroll
    for (int i = 0; i < NSc; ++i) {
#pragma unroll
      for (int jj = 0; jj < 3; ++jj)
        wfcr[i * 3 + jj] = (jj < jn) ? f1w[(i * COc + lane) * NCc + j0 + jj] : 0.0f;
    }
    float bj[3];
#pragma unroll
    for (int jj = 0; jj < 3; ++jj) bj[jj] = (jj < jn) ? f1b[j0 + jj] : 0.0f;

    // padded CSR in registers for hop waves 0-3
    int esrc[MAXDEG];
    float enrm[MAXDEG];
    if (w < 4) {
      int nn = (lane < NSc) ? lane : 0;
#pragma unroll
      for (int j = 0; j < MAXDEG; ++j) {
        esrc[j] = srcP[nn * MAXDEG + j];
        enrm[j] = nrmP[nn * MAXDEG + j];
      }
    }

    float cm[5] = {0, 0, 0, 0, 0};
    float hm[3] = {0, 0, 0}, hsum[3] = {0, 0, 0};

    for (int t = 0; t < Tc; ++t) {
      // hops in registers (waves 0-3, channel = w), via ds_bpermute shuffles
      if (w < 4) {
        const int c = w;
        float h = 0.0f;
        if (lane < NSc)
          h = dbase[((lane + (c >> 1) * NSc) * 2 + (c & 1)) * Tc + t];
        if (lane < NSc) featsS[c][lane] = h;
#pragma unroll
        for (int k = 1; k <= 3; ++k) {
          float nh = 0.0f;
#pragma unroll
          for (int j = 0; j < MAXDEG; ++j)
            nh = fmaf(enrm[j], __shfl(h, esrc[j], 64), nh);
          h = nh;
          if (lane < NSc) featsS[k * 4 + c][lane] = h;
        }
      }
      __syncthreads();
      // conv + LIF: node i = w + 8q, lane = out channel
#pragma unroll
      for (int q = 0; q < 5; ++q) {
        int i = w + 8 * q;
        if (i < NSc) {
          float acc = bcv;
#pragma unroll
          for (int r = 0; r < 16; ++r) acc = fmaf(featsS[r][i], wc[r], acc);
          float old = cm[q];
          float m = (old * 0.2f) * ((old > 0.5f) ? 0.0f : 1.0f) + acc;
          cm[q] = m;
          unsigned long long wd = __ballot(m > 0.5f);
          if (lane == 0) spkwS[i] = wd;
        }
      }
      __syncthreads();
      // fc: binary-gated accumulate with register weights
      float a0 = 0.0f, a1 = 0.0f, a2 = 0.0f;
#pragma unroll
      for (int i = 0; i < NSc; ++i) {
        float g = (float)((spkwS[i] >> lane) & 1ull);
        a0 = fmaf(g, wfcr[i * 3 + 0], a0);
        a1 = fmaf(g, wfcr[i * 3 + 1], a1);
        a2 = fmaf(g, wfcr[i * 3 + 2], a2);
      }
#pragma unroll
      for (int off = 32; off >= 1; off >>= 1) {
        a0 += __shfl_xor(a0, off, 64);
        a1 += __shfl_xor(a1, off, 64);
        a2 += __shfl_xor(a2, off, 64);
      }
      float av[3] = {a0, a1, a2};
#pragma unroll
      for (int jj = 0; jj < 3; ++jj) {
        float m = hm[jj];
        m = (m * 0.2f) * ((m > 0.5f) ? 0.0f : 1.0f) + av[jj] + bj[jj];
        hm[jj] = m;
        hsum[jj] += (m > 0.5f) ? 1.0f : 0.0f;
      }
    }
    if (lane == 0) {
      for (int jj = 0; jj < jn; ++jj)
        outS[b * NCc + j0 + jj] = hsum[jj] / (float)Tc;
    }
  } else {
    // ================= TEMPORAL =================
    for (int n = tid; n < Tc + 1; n += 512) lroff[n] = roffT[n];
    for (int e = tid; e < ETc; e += 512) { lsrc[e] = srcT[e]; lnrm[e] = nrmT[e]; }

    float wc[16];
#pragma unroll
    for (int r = 0; r < 16; ++r) wc[r] = c2w[r * COc + lane];
    const float bcv = c2b[lane];
    float bj[3];
#pragma unroll
    for (int jj = 0; jj < 3; ++jj) bj[jj] = (jj < jn) ? tf1b[j0 + jj] : 0.0f;

    const float* p0 = wT + (size_t)j0 * (Tc * COc) + lane;
    const float* p1 = wT + (size_t)(j0 + 1) * (Tc * COc) + lane;
    const float* p2 = wT + (size_t)((jn > 2) ? j0 + 2 : j0) * (Tc * COc) + lane;

    float tm[41];
#pragma unroll
    for (int q = 0; q < 41; ++q) tm[q] = 0.0f;
    float hm[3] = {0, 0, 0}, hsum[3] = {0, 0, 0};

    __syncthreads();

    for (int s = 0; s < NSc; ++s) {
      // stage x_s [325][4], coalesced in t
#pragma unroll
      for (int k2 = 0; k2 < 3; ++k2) {
        int idx = tid + 512 * k2;
        if (idx < Tc * 4) {
          int c = idx / Tc, t = idx - c * Tc;
          int nn = (c & 2) ? (NSc + s) : s;
          featsT[t][c] = dbase[(nn * 2 + (c & 1)) * Tc + t];
        }
      }
      __syncthreads();
#pragma unroll
      for (int k = 1; k <= 3; ++k) {
#pragma unroll
        for (int k2 = 0; k2 < 3; ++k2) {
          int idx = tid + 512 * k2;
          if (idx < Tc * 4) {
            int t = idx >> 2, c = idx & 3;
            float v = 0.0f;
            for (int e = lroff[t]; e < lroff[t + 1]; ++e)
              v += lnrm[e] * featsT[lsrc[e]][(k - 1) * 4 + c];
            featsT[t][k * 4 + c] = v;
          }
        }
        __syncthreads();
      }
      // conv + LIF, node i = w + 8q
#pragma unroll
      for (int q = 0; q < 41; ++q) {
        int i = w + 8 * q;
        if (i < Tc) {
          const float4* f4 = (const float4*)featsT[i];
          float fv[16];
          *(float4*)&fv[0] = f4[0];
          *(float4*)&fv[4] = f4[1];
          *(float4*)&fv[8] = f4[2];
          *(float4*)&fv[12] = f4[3];
          float acc = bcv;
#pragma unroll
          for (int r = 0; r < 16; ++r) acc = fmaf(fv[r], wc[r], acc);
          float old = tm[q];
          float m = (old * 0.2f) * ((old > 0.5f) ? 0.0f : 1.0f) + acc;
          tm[q] = m;
          unsigned long long wd = __ballot(m > 0.5f);
          if (lane == 0) spkwT[i] = wd;
        }
      }
      __syncthreads();
      // fc: stream transposed weights (L2), gated accumulate
      float a0 = 0.0f, a1 = 0.0f, a2 = 0.0f;
#pragma unroll 5
      for (int i = 0; i < Tc; ++i) {
        float g = (float)((spkwT[i] >> lane) & 1ull);
        a0 = fmaf(g, p0[(size_t)i * COc], a0);
        a1 = fmaf(g, p1[(size_t)i * COc], a1);
        a2 = fmaf(g, p2[(size_t)i * COc], a2);
      }
#pragma unroll
      for (int off = 32; off >= 1; off >>= 1) {
        a0 += __shfl_xor(a0, off, 64);
        a1 += __shfl_xor(a1, off, 64);
        a2 += __shfl_xor(a2, off, 64);
      }
      float av[3] = {a0, a1, a2};
#pragma unroll
      for (int jj = 0; jj < 3; ++jj) {
        float m = hm[jj];
        m = (m * 0.2f) * ((m > 0.5f) ? 0.0f : 1.0f) + av[jj] + bj[jj];
        hm[jj] = m;
        hsum[jj] += (m > 0.5f) ? 1.0f : 0.0f;
      }
    }
    if (lane == 0) {
      for (int jj = 0; jj < jn; ++jj)
        outT[b * NCc + j0 + jj] = hsum[jj] / (float)NSc;
    }
  }
}

__global__ void combine_kernel(const float* __restrict__ a, const float* __restrict__ c,
                               float* __restrict__ o) {
  int i = blockIdx.x * 256 + threadIdx.x;
  if (i < Bc * NCc) o[i] = (a[i] + c[i]) * 0.5f;
}

extern "C" void kernel_launch(void* const* d_in, const int* in_sizes, int n_in,
                              void* d_out, int out_size, void* d_ws, size_t ws_size,
                              hipStream_t stream) {
  const float* data = (const float*)d_in[0];
  const int*   eiS  = (const int*)d_in[1];
  const int*   eiT  = (const int*)d_in[2];
  const float* c1w  = (const float*)d_in[3];
  const float* c1b  = (const float*)d_in[4];
  const float* c2w  = (const float*)d_in[5];
  const float* c2b  = (const float*)d_in[6];
  const float* f1w  = (const float*)d_in[7];
  const float* f1b  = (const float*)d_in[8];
  const float* tf1w = (const float*)d_in[9];
  const float* tf1b = (const float*)d_in[10];
  float* out = (float*)d_out;
  int* wsI = (int*)d_ws;
  float* wsF = (float*)d_ws;

  prep_graph<<<2, 256, 0, stream>>>(eiS, eiT, wsI, wsF);
  prep_wt<<<(NCc * Tc * COc + 255) / 256, 256, 0, stream>>>(tf1w, wsF + WS_WT);
  lif_kernel<<<2 * Bc, 512, 0, stream>>>(data,
                                         wsI + WS_ROFF_T, wsI + WS_SRC_T, wsF + WS_NRM_T,
                                         wsI + WS_SRCP, wsF + WS_NRMP,
                                         c1w, c1b, c2w, c2b, f1w, f1b,
                                         wsF + WS_WT, tf1b,
                                         wsF + WS_OUTS, wsF + WS_OUTT);
  combine_kernel<<<(Bc * NCc + 255) / 256, 256, 0, stream>>>(wsF + WS_OUTS,
                                                             wsF + WS_OUTT, out);
}